// Round 2
// baseline (502.343 us; speedup 1.0000x reference)
//
#include <hip/hip_runtime.h>
#include <hip/hip_bf16.h>
#include <cstdint>
#include <cstddef>

typedef unsigned short u16;
typedef unsigned int   u32;
typedef short bf16x8 __attribute__((ext_vector_type(8)));   // 8 bf16 = 4 VGPRs
typedef float f32x4  __attribute__((ext_vector_type(4)));

__device__ __forceinline__ float bf2f(u16 v){ return __uint_as_float(((u32)v)<<16); }
__device__ __forceinline__ u16 f2bf(float f){
  u32 x = __float_as_uint(f);
  return (u16)((x + 0x7FFFu + ((x>>16)&1u)) >> 16);   // round-to-nearest-even
}
__device__ __forceinline__ void atomAddF(float* p, float v){ unsafeAtomicAdd(p, v); }

// ---------------- zero helper ----------------
__global__ void kzero(int* p, int n){
  int i = blockIdx.x*blockDim.x + threadIdx.x;
  if(i < n) p[i] = 0;
}

// ---------------- per-side degree counts ----------------
__global__ void kdeg2(const int* __restrict__ ei0, const int* __restrict__ ei1,
                      int* __restrict__ deg0, int* __restrict__ deg1, int E){
  int e = blockIdx.x*blockDim.x + threadIdx.x;
  if(e >= E) return;
  atomicAdd(&deg0[ei0[e]], 1);
  atomicAdd(&deg1[ei1[e]], 1);
}

// ---------------- hierarchical exclusive scan (3 phases) ----------------
__global__ __launch_bounds__(256) void ktilesum(const int* __restrict__ deg0,
                                                const int* __restrict__ deg1,
                                                int* __restrict__ tsum,
                                                int N, int nt){
  __shared__ int sh[256];
  const int b = blockIdx.x;
  const int* deg = (b < nt) ? deg0 : deg1;
  const int tile = (b < nt) ? b : b - nt;
  const int t = threadIdx.x;
  const int i = tile*256 + t;
  sh[t] = (i < N) ? deg[i] : 0;
  __syncthreads();
  for(int s = 128; s > 0; s >>= 1){
    if(t < s) sh[t] += sh[t+s];
    __syncthreads();
  }
  if(t == 0) tsum[b] = sh[0];
}
__global__ __launch_bounds__(256) void kmid(int* __restrict__ tsum,
                                            int* __restrict__ off0,
                                            int* __restrict__ off1,
                                            int N, int nt){
  __shared__ int sh[256];
  const int b = blockIdx.x;
  int* ts = tsum + b*nt;
  const int t = threadIdx.x;
  sh[t] = (t < nt) ? ts[t] : 0;
  __syncthreads();
  for(int s = 1; s < 256; s <<= 1){
    int x = (t >= s) ? sh[t-s] : 0;
    __syncthreads();
    sh[t] += x;
    __syncthreads();
  }
  if(t < nt) ts[t] = (t == 0) ? 0 : sh[t-1];
  if(t == 255){ int* off = b ? off1 : off0; off[N] = sh[255]; }
}
// phase 3: intra-tile scan + tile base -> off[]; blocks b<nt also emit dinv
__global__ __launch_bounds__(256) void kapply(const int* __restrict__ deg0,
                                              const int* __restrict__ deg1,
                                              const int* __restrict__ tsum,
                                              int* __restrict__ off0,
                                              int* __restrict__ off1,
                                              float* __restrict__ dinv,
                                              int N, int nt){
  __shared__ int sh[256];
  const int b = blockIdx.x;
  const int* deg = (b < nt) ? deg0 : deg1;
  int*       off = (b < nt) ? off0 : off1;
  const int tile = (b < nt) ? b : b - nt;
  const int base = tsum[b];
  const int t = threadIdx.x;
  const int i = tile*256 + t;
  sh[t] = (i < N) ? deg[i] : 0;
  __syncthreads();
  for(int s = 1; s < 256; s <<= 1){
    int x = (t >= s) ? sh[t-s] : 0;
    __syncthreads();
    sh[t] += x;
    __syncthreads();
  }
  if(i < N){
    off[i] = base + ((t == 0) ? 0 : sh[t-1]);
    if(b < nt){
      int d = deg0[i] + deg1[i];
      dinv[i] = (d > 1) ? (1.f/(float)d) : 0.f;   // deg==1 hyperedges dropped
    }
  }
}

// ---------------- counting-sort + per-edge SoA descriptors ----------------
// euv[pos]  = u | (v<<16)         (N < 65536)
// coef[pos] = (rc, iu*rc, iv*rc, ie)
// ebat[pos] = batch id (< 256)
__global__ void kperm(const int* __restrict__ ei0, const int* __restrict__ ei1,
                      const float* __restrict__ nimp, const float* __restrict__ dinv,
                      const int* __restrict__ batch, const int* __restrict__ off0,
                      int* __restrict__ cur0, u32* __restrict__ euv,
                      f32x4* __restrict__ coef, unsigned char* __restrict__ ebat,
                      int* __restrict__ orig, float* __restrict__ imp, int E){
  int e = blockIdx.x*blockDim.x + threadIdx.x;
  if(e >= E) return;
  int u = ei0[e], v = ei1[e];
  int pos = off0[u] + atomicAdd(&cur0[u], 1);
  float iu = dinv[u], iv = dinv[v];
  float rc = (iu > 0.f && iv > 0.f) ? (1.f/3.f)
           : ((iu > 0.f || iv > 0.f) ? 0.5f : 1.f);
  float ie = fminf(nimp[u], nimp[v]);
  euv[pos]  = (u32)u | ((u32)v << 16);
  f32x4 c; c.x = rc; c.y = iu*rc; c.z = iv*rc; c.w = ie;
  coef[pos] = c;
  ebat[pos] = (unsigned char)batch[u];
  orig[pos] = e;
  imp[pos]  = ie;
}

// ---------------- v-side incidence list (sorted edge ids) ----------------
__global__ void kfillv(const u32* __restrict__ euv, const int* __restrict__ off1,
                       int* __restrict__ cur1, int* __restrict__ list1, int E){
  int p = blockIdx.x*blockDim.x + threadIdx.x;
  if(p >= E) return;
  int v = (int)(euv[p] >> 16);
  list1[off1[v] + atomicAdd(&cur1[v], 1)] = p;
}

// ---------------- W -> fragment-ready layout (all 3 layers, one launch) -------
__global__ void kprepw(const float* __restrict__ W0, u16* __restrict__ wf0,
                       const float* __restrict__ W1, u16* __restrict__ wf1,
                       const float* __restrict__ W2, u16* __restrict__ wf2){
  const int b = blockIdx.x;
  const float* W; u16* wf; int NC, sbase;
  if(b == 0){ W = W0; wf = wf0; NC = 1; sbase = 0; }
  else if(b <= 2){ W = W1; wf = wf1; NC = 2; sbase = (b-1)*256; }
  else { W = W2; wf = wf2; NC = 2; sbase = (b-3)*256; }
  int s = sbase + threadIdx.x;
  if(s >= 4*NC*64) return;
  int lane = s & 63;
  int c    = (s >> 6) % NC;
  int tt   = s / (NC*64);
  int n  = tt*16 + (lane & 15);
  int k0 = c*32 + (lane >> 4)*8;
  #pragma unroll
  for(int j = 0; j < 8; j++)
    wf[(size_t)s*8 + j] = f2bf(W[(size_t)(k0 + j)*64 + n]);
}

// ---------------- layer 0: MFMA GEMM (edge_attr[orig]*imp @ W0) ---------------
__global__ __launch_bounds__(256) void kgemm0(const float* __restrict__ srcf,
                                              u16* __restrict__ buf,
                                              const u16* __restrict__ wf,
                                              const float* __restrict__ imp,
                                              const int* __restrict__ orig,
                                              int E){
  const int t    = threadIdx.x;
  const int wv   = t >> 6;
  const int lane = t & 63;
  const int quad = lane >> 4;
  const int l15  = lane & 15;
  const int row0 = blockIdx.x*64 + wv*16;
  if(row0 >= E) return;                      // E % 16 == 0

  bf16x8 bfr[4];
  #pragma unroll
  for(int i = 0; i < 4; i++)
    bfr[i] = *(const bf16x8*)(wf + ((size_t)i*64 + lane)*8);

  const int myrow = row0 + l15;
  const int oe = orig[myrow];
  const float* s = srcf + (size_t)oe*32 + quad*8;
  const float sc = imp[myrow];
  f32x4 v0 = *(const f32x4*)s;
  f32x4 v1 = *(const f32x4*)(s+4);
  bf16x8 afr;
  afr[0]=(short)f2bf(v0.x*sc); afr[1]=(short)f2bf(v0.y*sc);
  afr[2]=(short)f2bf(v0.z*sc); afr[3]=(short)f2bf(v0.w*sc);
  afr[4]=(short)f2bf(v1.x*sc); afr[5]=(short)f2bf(v1.y*sc);
  afr[6]=(short)f2bf(v1.z*sc); afr[7]=(short)f2bf(v1.w*sc);

  #pragma unroll
  for(int tt = 0; tt < 4; tt++){
    f32x4 a = {0.f,0.f,0.f,0.f};
    a = __builtin_amdgcn_mfma_f32_16x16x32_bf16(afr, bfr[tt], a, 0, 0, 0);
    const int n = tt*16 + l15;
    #pragma unroll
    for(int r = 0; r < 4; r++)
      buf[(size_t)(row0 + quad*4 + r)*64 + n] = f2bf(a[r]);
  }
}

// ---------------- aggregate: 8 rows per wave-instr, col-block layout ----------
// lane = (rsub = lane>>3 row-in-group, cb = lane&7 col-block of 8 cols)
__global__ __launch_bounds__(256) void kagg(const u16* __restrict__ buf,
                                            const int* __restrict__ off0,
                                            const int* __restrict__ off1,
                                            const int* __restrict__ list1,
                                            u16* __restrict__ heb, int N){
  const int t = threadIdx.x, wv = t >> 6, lane = t & 63;
  const int n = blockIdx.x*4 + wv;
  if(n >= N) return;
  const int rsub = lane >> 3, cb = lane & 7;
  float acc[8];
  #pragma unroll
  for(int k = 0; k < 8; k++) acc[k] = 0.f;

  auto accum = [&](uint4 x){
    acc[0] += bf2f((u16)x.x); acc[1] += bf2f((u16)(x.x>>16));
    acc[2] += bf2f((u16)x.y); acc[3] += bf2f((u16)(x.y>>16));
    acc[4] += bf2f((u16)x.z); acc[5] += bf2f((u16)(x.z>>16));
    acc[6] += bf2f((u16)x.w); acc[7] += bf2f((u16)(x.w>>16));
  };
  const uint4 zero4 = {0,0,0,0};

  // u-side: contiguous rows [off0[n], off0[n+1])
  {
    const int s0 = off0[n], d0 = off0[n+1] - s0;
    const u16* base = buf + (size_t)s0*64;
    int j = 0;
    for(; j + 8 <= d0; j += 8)
      accum(*(const uint4*)(base + (size_t)(j+rsub)*64 + cb*8));
    if(j < d0)
      accum((rsub < d0-j) ? *(const uint4*)(base + (size_t)(j+rsub)*64 + cb*8) : zero4);
  }
  // v-side: random rows via list1
  {
    const int s1 = off1[n], d1 = off1[n+1] - s1;
    int j = 0;
    for(; j + 8 <= d1; j += 8){
      int e = list1[s1 + j + rsub];
      accum(*(const uint4*)(buf + (size_t)e*64 + cb*8));
    }
    if(j < d1){
      uint4 x = zero4;
      if(rsub < d1-j){
        int e = list1[s1 + j + rsub];
        x = *(const uint4*)(buf + (size_t)e*64 + cb*8);
      }
      accum(x);
    }
  }
  // reduce across rsub (lanes differing in bits 3..5)
  #pragma unroll
  for(int m = 8; m <= 32; m <<= 1)
    #pragma unroll
    for(int k = 0; k < 8; k++) acc[k] += __shfl_xor(acc[k], m);
  // write: rsub==0 lanes store 8 cols (16 B)
  if(rsub == 0){
    u32 o[4];
    #pragma unroll
    for(int k = 0; k < 4; k++)
      o[k] = (u32)f2bf(acc[2*k]) | ((u32)f2bf(acc[2*k+1]) << 16);
    *(uint4*)(heb + (size_t)n*64 + cb*8) = make_uint4(o[0],o[1],o[2],o[3]);
  }
}

// ---------------- fused: gather + epilogue + register-pool (+ GEMM) ------------
// Depth-2 software pipeline: two 48-load gather banks (A/B) ping-pong so the
// epilogue+MFMA+store of group g always overlaps the in-flight gathers of g+1.
__device__ __forceinline__ void issue16(const u16* __restrict__ heb,
                                        const u16* __restrict__ buf,
                                        int rr, int lane, u32 uvp,
                                        u16 (&bv)[16], u16 (&hu)[16], u16 (&hv)[16]){
  #pragma unroll
  for(int q = 0; q < 16; q++){
    const u32 uv = (u32)__shfl((int)uvp, q);
    hv[q] = heb[(size_t)(uv >> 16)*64 + lane];
    hu[q] = heb[(size_t)(uv & 0xffffu)*64 + lane];
    bv[q] = buf[(size_t)(rr + q)*64 + lane];
  }
}

template<bool DO_GEMM>
__device__ __forceinline__ void cons16(u16* __restrict__ buf, u16* hTw,
                                       const bf16x8 (&bfr)[8], float bd,
                                       int rr, int lane, int quad, int l15,
                                       f32x4 cf, int bt,
                                       u16 (&bv)[16], u16 (&hu)[16], u16 (&hv)[16],
                                       float& pool, int& cur_g,
                                       float* __restrict__ ghL){
  #pragma unroll
  for(int q = 0; q < 16; q++){
    const float rc   = __shfl(cf.x, q);
    const float iurc = __shfl(cf.y, q);
    const float ivrc = __shfl(cf.z, q);
    const float ie   = __shfl(cf.w, q);
    const int   bq   = __shfl(bt, q);
    float o = fmaxf(fmaf(bf2f(bv[q]), rc,
                    fmaf(bf2f(hu[q]), iurc,
                    fmaf(bf2f(hv[q]), ivrc, bd))), 0.f) * ie;
    if(bq != cur_g){                        // wave-uniform branch
      if(cur_g >= 0) atomAddF(&ghL[cur_g*192 + lane], pool);
      pool = 0.f;
      cur_g = bq;
    }
    pool += o;
    if(DO_GEMM) hTw[q*72 + lane] = f2bf(o);
  }
  if(DO_GEMM){
    bf16x8 afr0 = *(const bf16x8*)&hTw[l15*72 + quad*8];
    bf16x8 afr1 = *(const bf16x8*)&hTw[l15*72 + 32 + quad*8];
    #pragma unroll
    for(int tt = 0; tt < 4; tt++){
      f32x4 a = {0.f,0.f,0.f,0.f};
      a = __builtin_amdgcn_mfma_f32_16x16x32_bf16(afr0, bfr[tt*2+0], a, 0, 0, 0);
      a = __builtin_amdgcn_mfma_f32_16x16x32_bf16(afr1, bfr[tt*2+1], a, 0, 0, 0);
      const int n = tt*16 + l15;
      #pragma unroll
      for(int r = 0; r < 4; r++)
        buf[(size_t)(rr + quad*4 + r)*64 + n] = f2bf(a[r]);
    }
  }
}

template<bool DO_GEMM>
__global__ __launch_bounds__(256, 3) void kfused(u16* __restrict__ buf,   // r/w
                                                 const u16* __restrict__ heb,
                                                 const u32* __restrict__ euv,
                                                 const f32x4* __restrict__ coef,
                                                 const unsigned char* __restrict__ ebat,
                                                 const float* __restrict__ bias,
                                                 const u16* __restrict__ wf,
                                                 float* __restrict__ ghL,  // gh + layer*64
                                                 int E){
  constexpr int HTSZ = DO_GEMM ? 4*16*72 : 4;       // 16 rows x 72 per wave
  __shared__ __align__(16) u16 hT[HTSZ];
  const int t = threadIdx.x, wv = t >> 6, lane = t & 63;
  const int quad = lane >> 4, l15 = lane & 15;
  const float bd = bias[lane];

  bf16x8 bfr[8];
  if(DO_GEMM){
    #pragma unroll
    for(int i = 0; i < 8; i++)
      bfr[i] = *(const bf16x8*)(wf + ((size_t)i*64 + lane)*8);
  }

  float pool = 0.f;
  int cur_g = -1;
  const int base = blockIdx.x*256 + wv*64;   // wave owns 64 contiguous edges
  u16* hTw = DO_GEMM ? &hT[wv*1152] : &hT[0];

  const int r0 = base, r1 = base+16, r2 = base+32, r3 = base+48;
  const bool a0 = r0 < E, a1 = r1 < E, a2 = r2 < E, a3 = r3 < E;   // E%16==0

  // ---- all 4 descriptor banks up-front (lane l15 holds edge rr+l15) ----
  u32 uv0=0,uv1=0,uv2=0,uv3=0; int bt0=0,bt1=0,bt2=0,bt3=0;
  f32x4 cf0={0,0,0,0}, cf1={0,0,0,0}, cf2={0,0,0,0}, cf3={0,0,0,0};
  if(a0){ uv0 = euv[r0+l15]; cf0 = coef[r0+l15]; bt0 = (int)ebat[r0+l15]; }
  if(a1){ uv1 = euv[r1+l15]; cf1 = coef[r1+l15]; bt1 = (int)ebat[r1+l15]; }
  if(a2){ uv2 = euv[r2+l15]; cf2 = coef[r2+l15]; bt2 = (int)ebat[r2+l15]; }
  if(a3){ uv3 = euv[r3+l15]; cf3 = coef[r3+l15]; bt3 = (int)ebat[r3+l15]; }

  u16 bvA[16], huA[16], hvA[16];
  u16 bvB[16], huB[16], hvB[16];

  // ---- pipelined schedule: issue g+1 before consuming g ----
  if(a0) issue16(heb, buf, r0, lane, uv0, bvA, huA, hvA);
  if(a1) issue16(heb, buf, r1, lane, uv1, bvB, huB, hvB);
  if(a0) cons16<DO_GEMM>(buf, hTw, bfr, bd, r0, lane, quad, l15, cf0, bt0,
                         bvA, huA, hvA, pool, cur_g, ghL);
  if(a2) issue16(heb, buf, r2, lane, uv2, bvA, huA, hvA);
  if(a1) cons16<DO_GEMM>(buf, hTw, bfr, bd, r1, lane, quad, l15, cf1, bt1,
                         bvB, huB, hvB, pool, cur_g, ghL);
  if(a3) issue16(heb, buf, r3, lane, uv3, bvB, huB, hvB);
  if(a2) cons16<DO_GEMM>(buf, hTw, bfr, bd, r2, lane, quad, l15, cf2, bt2,
                         bvA, huA, hvA, pool, cur_g, ghL);
  if(a3) cons16<DO_GEMM>(buf, hTw, bfr, bd, r3, lane, quad, l15, cf3, bt3,
                         bvB, huB, hvB, pool, cur_g, ghL);

  if(cur_g >= 0) atomAddF(&ghL[cur_g*192 + lane], pool);
}

__global__ void kfinal(const float* __restrict__ gh, float* __restrict__ out, int n){
  int i = blockIdx.x*blockDim.x + threadIdx.x;
  if(i < n) out[i] = gh[i];   // reference output dtype = float32
}

// ---------------- host ----------------
extern "C" void kernel_launch(void* const* d_in, const int* in_sizes, int n_in,
                              void* d_out, int out_size, void* d_ws, size_t ws_size,
                              hipStream_t stream) {
  const float* edge_attr = (const float*)d_in[1];
  const int*   ei        = (const int*)d_in[2];
  const int*   batch     = (const int*)d_in[3];
  const float* nimp      = (const float*)d_in[4];
  const float* Ws[3] = { (const float*)d_in[5], (const float*)d_in[7], (const float*)d_in[9] };
  const float* bs[3] = { (const float*)d_in[6], (const float*)d_in[8], (const float*)d_in[10] };

  const int E = in_sizes[1] / 32;   // edge_attr is (E, 32)
  const int N = in_sizes[4];        // node_imp is (N,)
  const int* ei0 = ei;
  const int* ei1 = ei + E;

  char* p = (char*)d_ws;
  auto carve = [&](size_t bytes)->char*{
    char* r = p; p += (bytes + 255) & ~(size_t)255; return r;
  };
  const int nt = (N + 255)/256;
  float* imp   = (float*)carve((size_t)E*4);
  int*   deg0  = (int*)  carve((size_t)4*N*4);       // deg0|deg1|cur0|cur1
  int*   deg1  = deg0 + N;
  int*   cur0  = deg0 + 2*N;
  int*   cur1  = deg0 + 3*N;
  float* dinv  = (float*)carve((size_t)N*4);
  int*   off0  = (int*)  carve((size_t)(N+1)*4);
  int*   off1  = (int*)  carve((size_t)(N+1)*4);
  int*   tsum  = (int*)  carve((size_t)2*nt*4);
  int*   orig  = (int*)  carve((size_t)E*4);
  int*   list1 = (int*)  carve((size_t)E*4);
  u32*   euv   = (u32*)  carve((size_t)E*4);
  f32x4* coef  = (f32x4*)carve((size_t)E*16);
  unsigned char* ebat = (unsigned char*)carve((size_t)E);
  u16*   heb   = (u16*)  carve((size_t)N*64*2);
  u16*   buf   = (u16*)  carve((size_t)E*64*2);      // xw / h' in-place
  float* gh    = (float*)carve((size_t)64*192*4);
  u16*   wfs[3];
  for(int l = 0; l < 3; l++) wfs[l] = (u16*)carve((size_t)4096*2);

  kzero<<<(4*N+255)/256, 256, 0, stream>>>(deg0, 4*N);
  kzero<<<(12288+255)/256, 256, 0, stream>>>((int*)gh, 12288);
  kdeg2<<<(E+255)/256, 256, 0, stream>>>(ei0, ei1, deg0, deg1, E);
  ktilesum<<<2*nt, 256, 0, stream>>>(deg0, deg1, tsum, N, nt);
  kmid<<<2, 256, 0, stream>>>(tsum, off0, off1, N, nt);
  kapply<<<2*nt, 256, 0, stream>>>(deg0, deg1, tsum, off0, off1, dinv, N, nt);
  kperm<<<(E+255)/256, 256, 0, stream>>>(ei0, ei1, nimp, dinv, batch, off0, cur0,
                                         euv, coef, ebat, orig, imp, E);
  kfillv<<<(E+255)/256, 256, 0, stream>>>(euv, off1, cur1, list1, E);
  kprepw<<<5, 256, 0, stream>>>(Ws[0], wfs[0], Ws[1], wfs[1], Ws[2], wfs[2]);

  const int nbG = (E + 63)/64;
  const int nbA = (N + 3)/4;
  const int nbF = (E + 255)/256;   // contiguous 256-edge chunk per block

  kgemm0<<<nbG, 256, 0, stream>>>(edge_attr, buf, wfs[0], imp, orig, E);
  kagg<<<nbA, 256, 0, stream>>>(buf, off0, off1, list1, heb, N);
  kfused<true ><<<nbF, 256, 0, stream>>>(buf, heb, euv, coef, ebat, bs[0], wfs[1], gh + 0*64, E);
  kagg<<<nbA, 256, 0, stream>>>(buf, off0, off1, list1, heb, N);
  kfused<true ><<<nbF, 256, 0, stream>>>(buf, heb, euv, coef, ebat, bs[1], wfs[2], gh + 1*64, E);
  kagg<<<nbA, 256, 0, stream>>>(buf, off0, off1, list1, heb, N);
  kfused<false><<<nbF, 256, 0, stream>>>(buf, heb, euv, coef, ebat, bs[2], nullptr, gh + 2*64, E);
  kfinal<<<(12288+255)/256, 256, 0, stream>>>(gh, (float*)d_out, 12288);
}

// Round 3
// 447.493 us; speedup vs baseline: 1.1226x; 1.1226x over previous
//
#include <hip/hip_runtime.h>
#include <hip/hip_bf16.h>
#include <cstdint>
#include <cstddef>

typedef unsigned short u16;
typedef unsigned int   u32;
typedef short bf16x8 __attribute__((ext_vector_type(8)));   // 8 bf16 = 4 VGPRs
typedef float f32x4  __attribute__((ext_vector_type(4)));

__device__ __forceinline__ float bf2f(u16 v){ return __uint_as_float(((u32)v)<<16); }
__device__ __forceinline__ u16 f2bf(float f){
  u32 x = __float_as_uint(f);
  return (u16)((x + 0x7FFFu + ((x>>16)&1u)) >> 16);   // round-to-nearest-even
}
__device__ __forceinline__ void atomAddF(float* p, float v){ unsafeAtomicAdd(p, v); }
__device__ __forceinline__ float rlanef(float v, int q){
  return __int_as_float(__builtin_amdgcn_readlane(__float_as_int(v), q));
}

// ---------------- zero helper ----------------
__global__ void kzero(int* p, int n){
  int i = blockIdx.x*blockDim.x + threadIdx.x;
  if(i < n) p[i] = 0;
}

// ---------------- per-side degree counts ----------------
__global__ void kdeg2(const int* __restrict__ ei0, const int* __restrict__ ei1,
                      int* __restrict__ deg0, int* __restrict__ deg1, int E){
  int e = blockIdx.x*blockDim.x + threadIdx.x;
  if(e >= E) return;
  atomicAdd(&deg0[ei0[e]], 1);
  atomicAdd(&deg1[ei1[e]], 1);
}

// ---------------- hierarchical exclusive scan (3 phases) ----------------
__global__ __launch_bounds__(256) void ktilesum(const int* __restrict__ deg0,
                                                const int* __restrict__ deg1,
                                                int* __restrict__ tsum,
                                                int N, int nt){
  __shared__ int sh[256];
  const int b = blockIdx.x;
  const int* deg = (b < nt) ? deg0 : deg1;
  const int tile = (b < nt) ? b : b - nt;
  const int t = threadIdx.x;
  const int i = tile*256 + t;
  sh[t] = (i < N) ? deg[i] : 0;
  __syncthreads();
  for(int s = 128; s > 0; s >>= 1){
    if(t < s) sh[t] += sh[t+s];
    __syncthreads();
  }
  if(t == 0) tsum[b] = sh[0];
}
__global__ __launch_bounds__(256) void kmid(int* __restrict__ tsum,
                                            int* __restrict__ off0,
                                            int* __restrict__ off1,
                                            int N, int nt){
  __shared__ int sh[256];
  const int b = blockIdx.x;
  int* ts = tsum + b*nt;
  const int t = threadIdx.x;
  sh[t] = (t < nt) ? ts[t] : 0;
  __syncthreads();
  for(int s = 1; s < 256; s <<= 1){
    int x = (t >= s) ? sh[t-s] : 0;
    __syncthreads();
    sh[t] += x;
    __syncthreads();
  }
  if(t < nt) ts[t] = (t == 0) ? 0 : sh[t-1];
  if(t == 255){ int* off = b ? off1 : off0; off[N] = sh[255]; }
}
// phase 3: intra-tile scan + tile base -> off[]; blocks b<nt also emit dinv
__global__ __launch_bounds__(256) void kapply(const int* __restrict__ deg0,
                                              const int* __restrict__ deg1,
                                              const int* __restrict__ tsum,
                                              int* __restrict__ off0,
                                              int* __restrict__ off1,
                                              float* __restrict__ dinv,
                                              int N, int nt){
  __shared__ int sh[256];
  const int b = blockIdx.x;
  const int* deg = (b < nt) ? deg0 : deg1;
  int*       off = (b < nt) ? off0 : off1;
  const int tile = (b < nt) ? b : b - nt;
  const int base = tsum[b];
  const int t = threadIdx.x;
  const int i = tile*256 + t;
  sh[t] = (i < N) ? deg[i] : 0;
  __syncthreads();
  for(int s = 1; s < 256; s <<= 1){
    int x = (t >= s) ? sh[t-s] : 0;
    __syncthreads();
    sh[t] += x;
    __syncthreads();
  }
  if(i < N){
    off[i] = base + ((t == 0) ? 0 : sh[t-1]);
    if(b < nt){
      int d = deg0[i] + deg1[i];
      dinv[i] = (d > 1) ? (1.f/(float)d) : 0.f;   // deg==1 hyperedges dropped
    }
  }
}

// ---------------- counting-sort + per-edge SoA descriptors ----------------
// euv[pos]  = u | (v<<16)         (N < 65536)
// coef[pos] = (rc, iu*rc, iv*rc, ie)
// ebat[pos] = batch id (< 256)
__global__ void kperm(const int* __restrict__ ei0, const int* __restrict__ ei1,
                      const float* __restrict__ nimp, const float* __restrict__ dinv,
                      const int* __restrict__ batch, const int* __restrict__ off0,
                      int* __restrict__ cur0, u32* __restrict__ euv,
                      f32x4* __restrict__ coef, unsigned char* __restrict__ ebat,
                      int* __restrict__ orig, float* __restrict__ imp, int E){
  int e = blockIdx.x*blockDim.x + threadIdx.x;
  if(e >= E) return;
  int u = ei0[e], v = ei1[e];
  int pos = off0[u] + atomicAdd(&cur0[u], 1);
  float iu = dinv[u], iv = dinv[v];
  float rc = (iu > 0.f && iv > 0.f) ? (1.f/3.f)
           : ((iu > 0.f || iv > 0.f) ? 0.5f : 1.f);
  float ie = fminf(nimp[u], nimp[v]);
  euv[pos]  = (u32)u | ((u32)v << 16);
  f32x4 c; c.x = rc; c.y = iu*rc; c.z = iv*rc; c.w = ie;
  coef[pos] = c;
  ebat[pos] = (unsigned char)batch[u];
  orig[pos] = e;
  imp[pos]  = ie;
}

// ---------------- v-side incidence list (sorted edge ids) ----------------
__global__ void kfillv(const u32* __restrict__ euv, const int* __restrict__ off1,
                       int* __restrict__ cur1, int* __restrict__ list1, int E){
  int p = blockIdx.x*blockDim.x + threadIdx.x;
  if(p >= E) return;
  int v = (int)(euv[p] >> 16);
  list1[off1[v] + atomicAdd(&cur1[v], 1)] = p;
}

// ---------------- W -> fragment-ready layout (all 3 layers, one launch) -------
__global__ void kprepw(const float* __restrict__ W0, u16* __restrict__ wf0,
                       const float* __restrict__ W1, u16* __restrict__ wf1,
                       const float* __restrict__ W2, u16* __restrict__ wf2){
  const int b = blockIdx.x;
  const float* W; u16* wf; int NC, sbase;
  if(b == 0){ W = W0; wf = wf0; NC = 1; sbase = 0; }
  else if(b <= 2){ W = W1; wf = wf1; NC = 2; sbase = (b-1)*256; }
  else { W = W2; wf = wf2; NC = 2; sbase = (b-3)*256; }
  int s = sbase + threadIdx.x;
  if(s >= 4*NC*64) return;
  int lane = s & 63;
  int c    = (s >> 6) % NC;
  int tt   = s / (NC*64);
  int n  = tt*16 + (lane & 15);
  int k0 = c*32 + (lane >> 4)*8;
  #pragma unroll
  for(int j = 0; j < 8; j++)
    wf[(size_t)s*8 + j] = f2bf(W[(size_t)(k0 + j)*64 + n]);
}

// ---------------- layer 0: MFMA GEMM (edge_attr[orig]*imp @ W0) ---------------
__global__ __launch_bounds__(256) void kgemm0(const float* __restrict__ srcf,
                                              u16* __restrict__ buf,
                                              const u16* __restrict__ wf,
                                              const float* __restrict__ imp,
                                              const int* __restrict__ orig,
                                              int E){
  const int t    = threadIdx.x;
  const int wv   = t >> 6;
  const int lane = t & 63;
  const int quad = lane >> 4;
  const int l15  = lane & 15;
  const int row0 = blockIdx.x*64 + wv*16;
  if(row0 >= E) return;                      // E % 16 == 0

  bf16x8 bfr[4];
  #pragma unroll
  for(int i = 0; i < 4; i++)
    bfr[i] = *(const bf16x8*)(wf + ((size_t)i*64 + lane)*8);

  const int myrow = row0 + l15;
  const int oe = orig[myrow];
  const float* s = srcf + (size_t)oe*32 + quad*8;
  const float sc = imp[myrow];
  f32x4 v0 = *(const f32x4*)s;
  f32x4 v1 = *(const f32x4*)(s+4);
  bf16x8 afr;
  afr[0]=(short)f2bf(v0.x*sc); afr[1]=(short)f2bf(v0.y*sc);
  afr[2]=(short)f2bf(v0.z*sc); afr[3]=(short)f2bf(v0.w*sc);
  afr[4]=(short)f2bf(v1.x*sc); afr[5]=(short)f2bf(v1.y*sc);
  afr[6]=(short)f2bf(v1.z*sc); afr[7]=(short)f2bf(v1.w*sc);

  #pragma unroll
  for(int tt = 0; tt < 4; tt++){
    f32x4 a = {0.f,0.f,0.f,0.f};
    a = __builtin_amdgcn_mfma_f32_16x16x32_bf16(afr, bfr[tt], a, 0, 0, 0);
    const int n = tt*16 + l15;
    #pragma unroll
    for(int r = 0; r < 4; r++)
      buf[(size_t)(row0 + quad*4 + r)*64 + n] = f2bf(a[r]);
  }
}

// ---------------- aggregate: 8 rows per wave-instr, col-block layout ----------
// lane = (rsub = lane>>3 row-in-group, cb = lane&7 col-block of 8 cols)
__global__ __launch_bounds__(256) void kagg(const u16* __restrict__ buf,
                                            const int* __restrict__ off0,
                                            const int* __restrict__ off1,
                                            const int* __restrict__ list1,
                                            u16* __restrict__ heb, int N){
  const int t = threadIdx.x, wv = t >> 6, lane = t & 63;
  const int n = blockIdx.x*4 + wv;
  if(n >= N) return;
  const int rsub = lane >> 3, cb = lane & 7;
  float acc[8];
  #pragma unroll
  for(int k = 0; k < 8; k++) acc[k] = 0.f;

  auto accum = [&](uint4 x){
    acc[0] += bf2f((u16)x.x); acc[1] += bf2f((u16)(x.x>>16));
    acc[2] += bf2f((u16)x.y); acc[3] += bf2f((u16)(x.y>>16));
    acc[4] += bf2f((u16)x.z); acc[5] += bf2f((u16)(x.z>>16));
    acc[6] += bf2f((u16)x.w); acc[7] += bf2f((u16)(x.w>>16));
  };
  const uint4 zero4 = {0,0,0,0};

  // u-side: contiguous rows [off0[n], off0[n+1])
  {
    const int s0 = off0[n], d0 = off0[n+1] - s0;
    const u16* base = buf + (size_t)s0*64;
    int j = 0;
    for(; j + 8 <= d0; j += 8)
      accum(*(const uint4*)(base + (size_t)(j+rsub)*64 + cb*8));
    if(j < d0)
      accum((rsub < d0-j) ? *(const uint4*)(base + (size_t)(j+rsub)*64 + cb*8) : zero4);
  }
  // v-side: random rows via list1
  {
    const int s1 = off1[n], d1 = off1[n+1] - s1;
    int j = 0;
    for(; j + 8 <= d1; j += 8){
      int e = list1[s1 + j + rsub];
      accum(*(const uint4*)(buf + (size_t)e*64 + cb*8));
    }
    if(j < d1){
      uint4 x = zero4;
      if(rsub < d1-j){
        int e = list1[s1 + j + rsub];
        x = *(const uint4*)(buf + (size_t)e*64 + cb*8);
      }
      accum(x);
    }
  }
  // reduce across rsub (lanes differing in bits 3..5)
  #pragma unroll
  for(int m = 8; m <= 32; m <<= 1)
    #pragma unroll
    for(int k = 0; k < 8; k++) acc[k] += __shfl_xor(acc[k], m);
  // write: rsub==0 lanes store 8 cols (16 B)
  if(rsub == 0){
    u32 o[4];
    #pragma unroll
    for(int k = 0; k < 4; k++)
      o[k] = (u32)f2bf(acc[2*k]) | ((u32)f2bf(acc[2*k+1]) << 16);
    *(uint4*)(heb + (size_t)n*64 + cb*8) = make_uint4(o[0],o[1],o[2],o[3]);
  }
}

// ---------------- fused: gather + epilogue + register-pool (+ GEMM) ------------
// Round-1 schedule (issue-48 -> prefetch-desc -> consume), with ALL cross-lane
// broadcasts done via v_readlane (VALU->SGPR, no LDS) and scalar-based gather
// addressing (SALU address math, immediate offsets for the contiguous rows).
template<bool DO_GEMM>
__global__ __launch_bounds__(256, 3) void kfused(u16* __restrict__ buf,   // r/w
                                                 const u16* __restrict__ heb,
                                                 const u32* __restrict__ euv,
                                                 const f32x4* __restrict__ coef,
                                                 const unsigned char* __restrict__ ebat,
                                                 const float* __restrict__ bias,
                                                 const u16* __restrict__ wf,
                                                 float* __restrict__ ghL,  // gh + layer*64
                                                 int E){
  constexpr int HTSZ = DO_GEMM ? 4*16*72 : 4;       // 16 rows x 72 per wave
  __shared__ __align__(16) u16 hT[HTSZ];
  const int t = threadIdx.x, wv = t >> 6, lane = t & 63;
  const int quad = lane >> 4, l15 = lane & 15;
  const float bd = bias[lane];

  bf16x8 bfr[8];
  if(DO_GEMM){
    #pragma unroll
    for(int i = 0; i < 8; i++)
      bfr[i] = *(const bf16x8*)(wf + ((size_t)i*64 + lane)*8);
  }

  float pool = 0.f;
  int cur_g = -1;
  // wave-uniform base row, forced into SGPR
  const int base = __builtin_amdgcn_readfirstlane((int)(blockIdx.x*256) + wv*64);
  u16* hTw = DO_GEMM ? &hT[wv*1152] : &hT[0];

  // descriptor bank for group 0 (lane l15 holds edge base+l15)
  u32 uvp = 0; f32x4 cf = {0.f,0.f,0.f,0.f}; int bt = 0;
  if(base < E){                              // E % 16 == 0 -> base+15 < E
    uvp = euv[base + l15];
    cf  = coef[base + l15];
    bt  = (int)ebat[base + l15];
  }

  #pragma unroll
  for(int it = 0; it < 4; it++){
    const int r0 = base + it*16;
    if(r0 < E){
      // ---- issue all 48 gathers (scalar bases, imm offsets for bv) ----
      u16 bv[16], hu[16], hv[16];
      const u16* bufr = buf + (size_t)r0*64;          // SGPR base
      #pragma unroll
      for(int q = 0; q < 16; q++){
        const u32 uv = (u32)__builtin_amdgcn_readlane((int)uvp, q);  // SGPR
        hv[q] = heb[(size_t)(uv >> 16)*64 + lane];
        hu[q] = heb[(size_t)(uv & 0xffffu)*64 + lane];
        bv[q] = bufr[q*64 + lane];
      }
      // ---- prefetch next group's descriptors ----
      u32 uvpN = uvp; f32x4 cfN = cf; int btN = bt;
      if(it < 3){
        const int r1 = r0 + 16;
        if(r1 < E){
          uvpN = euv[r1 + l15];
          cfN  = coef[r1 + l15];
          btN  = (int)ebat[r1 + l15];
        }
      }
      // ---- batch bookkeeping: uniform fast path (boundaries are rare) ----
      const int bFirst = __builtin_amdgcn_readlane(bt, 0);
      const int bLast  = __builtin_amdgcn_readlane(bt, 15);
      if(bFirst != cur_g){
        if(cur_g >= 0) atomAddF(&ghL[cur_g*192 + lane], pool);
        pool = 0.f; cur_g = bFirst;
      }
      if(bFirst == bLast){
        #pragma unroll
        for(int q = 0; q < 16; q++){
          const float rc   = rlanef(cf.x, q);
          const float iurc = rlanef(cf.y, q);
          const float ivrc = rlanef(cf.z, q);
          const float ie   = rlanef(cf.w, q);
          float o = fmaxf(fmaf(bf2f(bv[q]), rc,
                          fmaf(bf2f(hu[q]), iurc,
                          fmaf(bf2f(hv[q]), ivrc, bd))), 0.f) * ie;
          pool += o;
          if(DO_GEMM) hTw[q*72 + lane] = f2bf(o);
        }
      } else {
        #pragma unroll
        for(int q = 0; q < 16; q++){
          const float rc   = rlanef(cf.x, q);
          const float iurc = rlanef(cf.y, q);
          const float ivrc = rlanef(cf.z, q);
          const float ie   = rlanef(cf.w, q);
          const int   bq   = __builtin_amdgcn_readlane(bt, q);
          float o = fmaxf(fmaf(bf2f(bv[q]), rc,
                          fmaf(bf2f(hu[q]), iurc,
                          fmaf(bf2f(hv[q]), ivrc, bd))), 0.f) * ie;
          if(bq != cur_g){                        // wave-uniform branch
            if(cur_g >= 0) atomAddF(&ghL[cur_g*192 + lane], pool);
            pool = 0.f; cur_g = bq;
          }
          pool += o;
          if(DO_GEMM) hTw[q*72 + lane] = f2bf(o);
        }
      }
      // ---- stage 2: MFMA these 16 rows (wave-local LDS, no barrier) ----
      if(DO_GEMM){
        bf16x8 afr0 = *(const bf16x8*)&hTw[l15*72 + quad*8];
        bf16x8 afr1 = *(const bf16x8*)&hTw[l15*72 + 32 + quad*8];
        #pragma unroll
        for(int tt = 0; tt < 4; tt++){
          f32x4 a = {0.f,0.f,0.f,0.f};
          a = __builtin_amdgcn_mfma_f32_16x16x32_bf16(afr0, bfr[tt*2+0], a, 0, 0, 0);
          a = __builtin_amdgcn_mfma_f32_16x16x32_bf16(afr1, bfr[tt*2+1], a, 0, 0, 0);
          const int n = tt*16 + l15;
          #pragma unroll
          for(int r = 0; r < 4; r++)
            buf[(size_t)(r0 + quad*4 + r)*64 + n] = f2bf(a[r]);
        }
      }
      uvp = uvpN; cf = cfN; bt = btN;
    }
  }
  if(cur_g >= 0) atomAddF(&ghL[cur_g*192 + lane], pool);
}

__global__ void kfinal(const float* __restrict__ gh, float* __restrict__ out, int n){
  int i = blockIdx.x*blockDim.x + threadIdx.x;
  if(i < n) out[i] = gh[i];   // reference output dtype = float32
}

// ---------------- host ----------------
extern "C" void kernel_launch(void* const* d_in, const int* in_sizes, int n_in,
                              void* d_out, int out_size, void* d_ws, size_t ws_size,
                              hipStream_t stream) {
  const float* edge_attr = (const float*)d_in[1];
  const int*   ei        = (const int*)d_in[2];
  const int*   batch     = (const int*)d_in[3];
  const float* nimp      = (const float*)d_in[4];
  const float* Ws[3] = { (const float*)d_in[5], (const float*)d_in[7], (const float*)d_in[9] };
  const float* bs[3] = { (const float*)d_in[6], (const float*)d_in[8], (const float*)d_in[10] };

  const int E = in_sizes[1] / 32;   // edge_attr is (E, 32)
  const int N = in_sizes[4];        // node_imp is (N,)
  const int* ei0 = ei;
  const int* ei1 = ei + E;

  char* p = (char*)d_ws;
  auto carve = [&](size_t bytes)->char*{
    char* r = p; p += (bytes + 255) & ~(size_t)255; return r;
  };
  const int nt = (N + 255)/256;
  float* imp   = (float*)carve((size_t)E*4);
  int*   deg0  = (int*)  carve((size_t)4*N*4);       // deg0|deg1|cur0|cur1
  int*   deg1  = deg0 + N;
  int*   cur0  = deg0 + 2*N;
  int*   cur1  = deg0 + 3*N;
  float* dinv  = (float*)carve((size_t)N*4);
  int*   off0  = (int*)  carve((size_t)(N+1)*4);
  int*   off1  = (int*)  carve((size_t)(N+1)*4);
  int*   tsum  = (int*)  carve((size_t)2*nt*4);
  int*   orig  = (int*)  carve((size_t)E*4);
  int*   list1 = (int*)  carve((size_t)E*4);
  u32*   euv   = (u32*)  carve((size_t)E*4);
  f32x4* coef  = (f32x4*)carve((size_t)E*16);
  unsigned char* ebat = (unsigned char*)carve((size_t)E);
  u16*   heb   = (u16*)  carve((size_t)N*64*2);
  u16*   buf   = (u16*)  carve((size_t)E*64*2);      // xw / h' in-place
  float* gh    = (float*)carve((size_t)64*192*4);
  u16*   wfs[3];
  for(int l = 0; l < 3; l++) wfs[l] = (u16*)carve((size_t)4096*2);

  kzero<<<(4*N+255)/256, 256, 0, stream>>>(deg0, 4*N);
  kzero<<<(12288+255)/256, 256, 0, stream>>>((int*)gh, 12288);
  kdeg2<<<(E+255)/256, 256, 0, stream>>>(ei0, ei1, deg0, deg1, E);
  ktilesum<<<2*nt, 256, 0, stream>>>(deg0, deg1, tsum, N, nt);
  kmid<<<2, 256, 0, stream>>>(tsum, off0, off1, N, nt);
  kapply<<<2*nt, 256, 0, stream>>>(deg0, deg1, tsum, off0, off1, dinv, N, nt);
  kperm<<<(E+255)/256, 256, 0, stream>>>(ei0, ei1, nimp, dinv, batch, off0, cur0,
                                         euv, coef, ebat, orig, imp, E);
  kfillv<<<(E+255)/256, 256, 0, stream>>>(euv, off1, cur1, list1, E);
  kprepw<<<5, 256, 0, stream>>>(Ws[0], wfs[0], Ws[1], wfs[1], Ws[2], wfs[2]);

  const int nbG = (E + 63)/64;
  const int nbA = (N + 3)/4;
  const int nbF = (E + 255)/256;   // contiguous 256-edge chunk per block

  kgemm0<<<nbG, 256, 0, stream>>>(edge_attr, buf, wfs[0], imp, orig, E);
  kagg<<<nbA, 256, 0, stream>>>(buf, off0, off1, list1, heb, N);
  kfused<true ><<<nbF, 256, 0, stream>>>(buf, heb, euv, coef, ebat, bs[0], wfs[1], gh + 0*64, E);
  kagg<<<nbA, 256, 0, stream>>>(buf, off0, off1, list1, heb, N);
  kfused<true ><<<nbF, 256, 0, stream>>>(buf, heb, euv, coef, ebat, bs[1], wfs[2], gh + 1*64, E);
  kagg<<<nbA, 256, 0, stream>>>(buf, off0, off1, list1, heb, N);
  kfused<false><<<nbF, 256, 0, stream>>>(buf, heb, euv, coef, ebat, bs[2], nullptr, gh + 2*64, E);
  kfinal<<<(12288+255)/256, 256, 0, stream>>>(gh, (float*)d_out, 12288);
}

// Round 4
// 432.471 us; speedup vs baseline: 1.1616x; 1.0347x over previous
//
#include <hip/hip_runtime.h>
#include <hip/hip_bf16.h>
#include <cstdint>
#include <cstddef>

typedef unsigned short u16;
typedef unsigned int   u32;
typedef short bf16x8 __attribute__((ext_vector_type(8)));   // 8 bf16 = 4 VGPRs
typedef float f32x4  __attribute__((ext_vector_type(4)));

// one 32-B record per sorted edge: a single cache line touch on scatter
struct __align__(16) ERec {
  u32 uv;            // u | (v<<16)
  float rc, iurc, ivrc;
  float ie; u32 bat; u32 pad0, pad1;
};

__device__ __forceinline__ float bf2f(u16 v){ return __uint_as_float(((u32)v)<<16); }
__device__ __forceinline__ u16 f2bf(float f){
  u32 x = __float_as_uint(f);
  return (u16)((x + 0x7FFFu + ((x>>16)&1u)) >> 16);   // round-to-nearest-even
}
__device__ __forceinline__ void atomAddF(float* p, float v){ unsafeAtomicAdd(p, v); }
__device__ __forceinline__ float rlanef(float v, int q){
  return __int_as_float(__builtin_amdgcn_readlane(__float_as_int(v), q));
}

// ---------------- zero helper ----------------
__global__ void kzero(int* p, int n){
  int i = blockIdx.x*blockDim.x + threadIdx.x;
  if(i < n) p[i] = 0;
}

// ---------------- per-side degree counts ----------------
__global__ void kdeg2(const int* __restrict__ ei0, const int* __restrict__ ei1,
                      int* __restrict__ deg0, int* __restrict__ deg1, int E){
  int e = blockIdx.x*blockDim.x + threadIdx.x;
  if(e >= E) return;
  atomicAdd(&deg0[ei0[e]], 1);
  atomicAdd(&deg1[ei1[e]], 1);
}

// ---------------- hierarchical exclusive scan (3 phases) ----------------
__global__ __launch_bounds__(256) void ktilesum(const int* __restrict__ deg0,
                                                const int* __restrict__ deg1,
                                                int* __restrict__ tsum,
                                                int N, int nt){
  __shared__ int sh[256];
  const int b = blockIdx.x;
  const int* deg = (b < nt) ? deg0 : deg1;
  const int tile = (b < nt) ? b : b - nt;
  const int t = threadIdx.x;
  const int i = tile*256 + t;
  sh[t] = (i < N) ? deg[i] : 0;
  __syncthreads();
  for(int s = 128; s > 0; s >>= 1){
    if(t < s) sh[t] += sh[t+s];
    __syncthreads();
  }
  if(t == 0) tsum[b] = sh[0];
}
__global__ __launch_bounds__(256) void kmid(int* __restrict__ tsum,
                                            int* __restrict__ off0,
                                            int* __restrict__ off1,
                                            int N, int nt){
  __shared__ int sh[256];
  const int b = blockIdx.x;
  int* ts = tsum + b*nt;
  const int t = threadIdx.x;
  sh[t] = (t < nt) ? ts[t] : 0;
  __syncthreads();
  for(int s = 1; s < 256; s <<= 1){
    int x = (t >= s) ? sh[t-s] : 0;
    __syncthreads();
    sh[t] += x;
    __syncthreads();
  }
  if(t < nt) ts[t] = (t == 0) ? 0 : sh[t-1];
  if(t == 255){ int* off = b ? off1 : off0; off[N] = sh[255]; }
}
// phase 3: intra-tile scan + tile base -> off[]; blocks b<nt also emit dinv
__global__ __launch_bounds__(256) void kapply(const int* __restrict__ deg0,
                                              const int* __restrict__ deg1,
                                              const int* __restrict__ tsum,
                                              int* __restrict__ off0,
                                              int* __restrict__ off1,
                                              float* __restrict__ dinv,
                                              int N, int nt){
  __shared__ int sh[256];
  const int b = blockIdx.x;
  const int* deg = (b < nt) ? deg0 : deg1;
  int*       off = (b < nt) ? off0 : off1;
  const int tile = (b < nt) ? b : b - nt;
  const int base = tsum[b];
  const int t = threadIdx.x;
  const int i = tile*256 + t;
  sh[t] = (i < N) ? deg[i] : 0;
  __syncthreads();
  for(int s = 1; s < 256; s <<= 1){
    int x = (t >= s) ? sh[t-s] : 0;
    __syncthreads();
    sh[t] += x;
    __syncthreads();
  }
  if(i < N){
    off[i] = base + ((t == 0) ? 0 : sh[t-1]);
    if(b < nt){
      int d = deg0[i] + deg1[i];
      dinv[i] = (d > 1) ? (1.f/(float)d) : 0.f;   // deg==1 hyperedges dropped
    }
  }
}

// ---------------- counting-sort: ONE 32B record scatter + coalesced sides ----
__global__ void kperm(const int* __restrict__ ei0, const int* __restrict__ ei1,
                      const float* __restrict__ nimp, const float* __restrict__ dinv,
                      const int* __restrict__ batch, const int* __restrict__ off0,
                      int* __restrict__ cur0, ERec* __restrict__ rec,
                      int* __restrict__ iperm, float* __restrict__ impO, int E){
  int e = blockIdx.x*blockDim.x + threadIdx.x;
  if(e >= E) return;
  int u = ei0[e], v = ei1[e];
  int pos = off0[u] + atomicAdd(&cur0[u], 1);
  float iu = dinv[u], iv = dinv[v];
  float rc = (iu > 0.f && iv > 0.f) ? (1.f/3.f)
           : ((iu > 0.f || iv > 0.f) ? 0.5f : 1.f);
  float ie = fminf(nimp[u], nimp[v]);
  ERec r;
  r.uv = (u32)u | ((u32)v << 16);
  r.rc = rc; r.iurc = iu*rc; r.ivrc = iv*rc;
  r.ie = ie; r.bat = (u32)batch[u]; r.pad0 = 0; r.pad1 = 0;
  rec[pos]  = r;          // single-line scattered store (2x dwordx4)
  iperm[e]  = pos;        // coalesced
  impO[e]   = ie;         // coalesced
}

// ---------------- v-side incidence list (all reads coalesced) ----------------
__global__ void kfillv(const int* __restrict__ ei1, const int* __restrict__ iperm,
                       const int* __restrict__ off1, int* __restrict__ cur1,
                       int* __restrict__ list1, int E){
  int e = blockIdx.x*blockDim.x + threadIdx.x;
  if(e >= E) return;
  int v = ei1[e];
  list1[off1[v] + atomicAdd(&cur1[v], 1)] = iperm[e];
}

// ---------------- W -> fragment-ready layout (all 3 layers, one launch) -------
__global__ void kprepw(const float* __restrict__ W0, u16* __restrict__ wf0,
                       const float* __restrict__ W1, u16* __restrict__ wf1,
                       const float* __restrict__ W2, u16* __restrict__ wf2){
  const int b = blockIdx.x;
  const float* W; u16* wf; int NC, sbase;
  if(b == 0){ W = W0; wf = wf0; NC = 1; sbase = 0; }
  else if(b <= 2){ W = W1; wf = wf1; NC = 2; sbase = (b-1)*256; }
  else { W = W2; wf = wf2; NC = 2; sbase = (b-3)*256; }
  int s = sbase + threadIdx.x;
  if(s >= 4*NC*64) return;
  int lane = s & 63;
  int c    = (s >> 6) % NC;
  int tt   = s / (NC*64);
  int n  = tt*16 + (lane & 15);
  int k0 = c*32 + (lane >> 4)*8;
  #pragma unroll
  for(int j = 0; j < 8; j++)
    wf[(size_t)s*8 + j] = f2bf(W[(size_t)(k0 + j)*64 + n]);
}

// ---------------- layer 0 GEMM: sequential reads, scattered 128B-row writes ---
__global__ __launch_bounds__(256) void kgemm0(const float* __restrict__ srcf,
                                              u16* __restrict__ buf,
                                              const u16* __restrict__ wf,
                                              const float* __restrict__ impO,
                                              const int* __restrict__ iperm,
                                              int E){
  const int t    = threadIdx.x;
  const int wv   = t >> 6;
  const int lane = t & 63;
  const int quad = lane >> 4;
  const int l15  = lane & 15;
  const int row0 = blockIdx.x*64 + wv*16;
  if(row0 >= E) return;                      // E % 16 == 0

  bf16x8 bfr[4];
  #pragma unroll
  for(int i = 0; i < 4; i++)
    bfr[i] = *(const bf16x8*)(wf + ((size_t)i*64 + lane)*8);

  const int myrow = row0 + l15;              // ORIGINAL edge order: streaming
  const float* s = srcf + (size_t)myrow*32 + quad*8;
  const float sc = impO[myrow];              // coalesced
  const int ip = iperm[myrow];               // coalesced; dest row in sorted space
  f32x4 v0 = *(const f32x4*)s;
  f32x4 v1 = *(const f32x4*)(s+4);
  bf16x8 afr;
  afr[0]=(short)f2bf(v0.x*sc); afr[1]=(short)f2bf(v0.y*sc);
  afr[2]=(short)f2bf(v0.z*sc); afr[3]=(short)f2bf(v0.w*sc);
  afr[4]=(short)f2bf(v1.x*sc); afr[5]=(short)f2bf(v1.y*sc);
  afr[6]=(short)f2bf(v1.z*sc); afr[7]=(short)f2bf(v1.w*sc);

  // dest rows for the 4 tile-rows this quad stores (one bpermute per r)
  int dr[4];
  #pragma unroll
  for(int r = 0; r < 4; r++) dr[r] = __shfl(ip, quad*4 + r);

  #pragma unroll
  for(int tt = 0; tt < 4; tt++){
    f32x4 a = {0.f,0.f,0.f,0.f};
    a = __builtin_amdgcn_mfma_f32_16x16x32_bf16(afr, bfr[tt], a, 0, 0, 0);
    const int n = tt*16 + l15;
    #pragma unroll
    for(int r = 0; r < 4; r++)
      buf[(size_t)dr[r]*64 + n] = f2bf(a[r]);
  }
}

// ---------------- aggregate: 8 rows per wave-instr, col-block layout ----------
// lane = (rsub = lane>>3 row-in-group, cb = lane&7 col-block of 8 cols)
__global__ __launch_bounds__(256) void kagg(const u16* __restrict__ buf,
                                            const int* __restrict__ off0,
                                            const int* __restrict__ off1,
                                            const int* __restrict__ list1,
                                            u16* __restrict__ heb, int N){
  const int t = threadIdx.x, wv = t >> 6, lane = t & 63;
  const int n = blockIdx.x*4 + wv;
  if(n >= N) return;
  const int rsub = lane >> 3, cb = lane & 7;
  float acc[8];
  #pragma unroll
  for(int k = 0; k < 8; k++) acc[k] = 0.f;

  auto accum = [&](uint4 x){
    acc[0] += bf2f((u16)x.x); acc[1] += bf2f((u16)(x.x>>16));
    acc[2] += bf2f((u16)x.y); acc[3] += bf2f((u16)(x.y>>16));
    acc[4] += bf2f((u16)x.z); acc[5] += bf2f((u16)(x.z>>16));
    acc[6] += bf2f((u16)x.w); acc[7] += bf2f((u16)(x.w>>16));
  };
  const uint4 zero4 = {0,0,0,0};

  // u-side: contiguous rows [off0[n], off0[n+1])
  {
    const int s0 = off0[n], d0 = off0[n+1] - s0;
    const u16* base = buf + (size_t)s0*64;
    int j = 0;
    for(; j + 8 <= d0; j += 8)
      accum(*(const uint4*)(base + (size_t)(j+rsub)*64 + cb*8));
    if(j < d0)
      accum((rsub < d0-j) ? *(const uint4*)(base + (size_t)(j+rsub)*64 + cb*8) : zero4);
  }
  // v-side: random rows via list1
  {
    const int s1 = off1[n], d1 = off1[n+1] - s1;
    int j = 0;
    for(; j + 8 <= d1; j += 8){
      int e = list1[s1 + j + rsub];
      accum(*(const uint4*)(buf + (size_t)e*64 + cb*8));
    }
    if(j < d1){
      uint4 x = zero4;
      if(rsub < d1-j){
        int e = list1[s1 + j + rsub];
        x = *(const uint4*)(buf + (size_t)e*64 + cb*8);
      }
      accum(x);
    }
  }
  // reduce across rsub (lanes differing in bits 3..5)
  #pragma unroll
  for(int m = 8; m <= 32; m <<= 1)
    #pragma unroll
    for(int k = 0; k < 8; k++) acc[k] += __shfl_xor(acc[k], m);
  // write: rsub==0 lanes store 8 cols (16 B)
  if(rsub == 0){
    u32 o[4];
    #pragma unroll
    for(int k = 0; k < 4; k++)
      o[k] = (u32)f2bf(acc[2*k]) | ((u32)f2bf(acc[2*k+1]) << 16);
    *(uint4*)(heb + (size_t)n*64 + cb*8) = make_uint4(o[0],o[1],o[2],o[3]);
  }
}

// ---------------- fused: gather + epilogue + register-pool (+ GEMM) ------------
// issue-48 -> prefetch-desc -> consume; readlane broadcasts; ERec descriptors.
template<bool DO_GEMM>
__global__ __launch_bounds__(256, 3) void kfused(u16* __restrict__ buf,   // r/w
                                                 const u16* __restrict__ heb,
                                                 const f32x4* __restrict__ rec4, // ERec as 2x f32x4
                                                 const float* __restrict__ bias,
                                                 const u16* __restrict__ wf,
                                                 float* __restrict__ ghL,  // gh + layer*64
                                                 int E){
  constexpr int HTSZ = DO_GEMM ? 4*16*72 : 4;       // 16 rows x 72 per wave
  __shared__ __align__(16) u16 hT[HTSZ];
  const int t = threadIdx.x, wv = t >> 6, lane = t & 63;
  const int quad = lane >> 4, l15 = lane & 15;
  const float bd = bias[lane];

  bf16x8 bfr[8];
  if(DO_GEMM){
    #pragma unroll
    for(int i = 0; i < 8; i++)
      bfr[i] = *(const bf16x8*)(wf + ((size_t)i*64 + lane)*8);
  }

  float pool = 0.f;
  int cur_g = -1;
  // wave-uniform base row, forced into SGPR
  const int base = __builtin_amdgcn_readfirstlane((int)(blockIdx.x*256) + wv*64);
  u16* hTw = DO_GEMM ? &hT[wv*1152] : &hT[0];

  // descriptor bank for group 0 (lane l15 holds edge base+l15)
  u32 uvp = 0; f32x4 cf = {0.f,0.f,0.f,0.f}; int bt = 0;
  if(base < E){                              // E % 16 == 0 -> base+15 < E
    f32x4 w0 = rec4[(size_t)(base+l15)*2];
    f32x4 w1 = rec4[(size_t)(base+l15)*2 + 1];
    uvp = __float_as_uint(w0.x);
    cf.x = w0.y; cf.y = w0.z; cf.z = w0.w; cf.w = w1.x;
    bt  = __float_as_int(w1.y);
  }

  #pragma unroll
  for(int it = 0; it < 4; it++){
    const int r0 = base + it*16;
    if(r0 < E){
      // ---- issue all 48 gathers (scalar bases, imm offsets for bv) ----
      u16 bv[16], hu[16], hv[16];
      const u16* bufr = buf + (size_t)r0*64;          // SGPR base
      #pragma unroll
      for(int q = 0; q < 16; q++){
        const u32 uv = (u32)__builtin_amdgcn_readlane((int)uvp, q);  // SGPR
        hv[q] = heb[(size_t)(uv >> 16)*64 + lane];
        hu[q] = heb[(size_t)(uv & 0xffffu)*64 + lane];
        bv[q] = bufr[q*64 + lane];
      }
      // ---- prefetch next group's descriptors ----
      u32 uvpN = uvp; f32x4 cfN = cf; int btN = bt;
      if(it < 3){
        const int r1 = r0 + 16;
        if(r1 < E){
          f32x4 w0 = rec4[(size_t)(r1+l15)*2];
          f32x4 w1 = rec4[(size_t)(r1+l15)*2 + 1];
          uvpN = __float_as_uint(w0.x);
          cfN.x = w0.y; cfN.y = w0.z; cfN.z = w0.w; cfN.w = w1.x;
          btN  = __float_as_int(w1.y);
        }
      }
      // ---- batch bookkeeping: uniform fast path (boundaries are rare) ----
      const int bFirst = __builtin_amdgcn_readlane(bt, 0);
      const int bLast  = __builtin_amdgcn_readlane(bt, 15);
      if(bFirst != cur_g){
        if(cur_g >= 0) atomAddF(&ghL[cur_g*192 + lane], pool);
        pool = 0.f; cur_g = bFirst;
      }
      if(bFirst == bLast){
        #pragma unroll
        for(int q = 0; q < 16; q++){
          const float rc   = rlanef(cf.x, q);
          const float iurc = rlanef(cf.y, q);
          const float ivrc = rlanef(cf.z, q);
          const float ie   = rlanef(cf.w, q);
          float o = fmaxf(fmaf(bf2f(bv[q]), rc,
                          fmaf(bf2f(hu[q]), iurc,
                          fmaf(bf2f(hv[q]), ivrc, bd))), 0.f) * ie;
          pool += o;
          if(DO_GEMM) hTw[q*72 + lane] = f2bf(o);
        }
      } else {
        #pragma unroll
        for(int q = 0; q < 16; q++){
          const float rc   = rlanef(cf.x, q);
          const float iurc = rlanef(cf.y, q);
          const float ivrc = rlanef(cf.z, q);
          const float ie   = rlanef(cf.w, q);
          const int   bq   = __builtin_amdgcn_readlane(bt, q);
          float o = fmaxf(fmaf(bf2f(bv[q]), rc,
                          fmaf(bf2f(hu[q]), iurc,
                          fmaf(bf2f(hv[q]), ivrc, bd))), 0.f) * ie;
          if(bq != cur_g){                        // wave-uniform branch
            if(cur_g >= 0) atomAddF(&ghL[cur_g*192 + lane], pool);
            pool = 0.f; cur_g = bq;
          }
          pool += o;
          if(DO_GEMM) hTw[q*72 + lane] = f2bf(o);
        }
      }
      // ---- stage 2: MFMA these 16 rows (wave-local LDS, no barrier) ----
      if(DO_GEMM){
        bf16x8 afr0 = *(const bf16x8*)&hTw[l15*72 + quad*8];
        bf16x8 afr1 = *(const bf16x8*)&hTw[l15*72 + 32 + quad*8];
        #pragma unroll
        for(int tt = 0; tt < 4; tt++){
          f32x4 a = {0.f,0.f,0.f,0.f};
          a = __builtin_amdgcn_mfma_f32_16x16x32_bf16(afr0, bfr[tt*2+0], a, 0, 0, 0);
          a = __builtin_amdgcn_mfma_f32_16x16x32_bf16(afr1, bfr[tt*2+1], a, 0, 0, 0);
          const int n = tt*16 + l15;
          #pragma unroll
          for(int r = 0; r < 4; r++)
            buf[(size_t)(r0 + quad*4 + r)*64 + n] = f2bf(a[r]);
        }
      }
      uvp = uvpN; cf = cfN; bt = btN;
    }
  }
  if(cur_g >= 0) atomAddF(&ghL[cur_g*192 + lane], pool);
}

__global__ void kfinal(const float* __restrict__ gh, float* __restrict__ out, int n){
  int i = blockIdx.x*blockDim.x + threadIdx.x;
  if(i < n) out[i] = gh[i];   // reference output dtype = float32
}

// ---------------- host ----------------
extern "C" void kernel_launch(void* const* d_in, const int* in_sizes, int n_in,
                              void* d_out, int out_size, void* d_ws, size_t ws_size,
                              hipStream_t stream) {
  const float* edge_attr = (const float*)d_in[1];
  const int*   ei        = (const int*)d_in[2];
  const int*   batch     = (const int*)d_in[3];
  const float* nimp      = (const float*)d_in[4];
  const float* Ws[3] = { (const float*)d_in[5], (const float*)d_in[7], (const float*)d_in[9] };
  const float* bs[3] = { (const float*)d_in[6], (const float*)d_in[8], (const float*)d_in[10] };

  const int E = in_sizes[1] / 32;   // edge_attr is (E, 32)
  const int N = in_sizes[4];        // node_imp is (N,)
  const int* ei0 = ei;
  const int* ei1 = ei + E;

  char* p = (char*)d_ws;
  auto carve = [&](size_t bytes)->char*{
    char* r = p; p += (bytes + 255) & ~(size_t)255; return r;
  };
  const int nt = (N + 255)/256;
  int*   deg0  = (int*)  carve((size_t)4*N*4);       // deg0|deg1|cur0|cur1
  int*   deg1  = deg0 + N;
  int*   cur0  = deg0 + 2*N;
  int*   cur1  = deg0 + 3*N;
  float* dinv  = (float*)carve((size_t)N*4);
  int*   off0  = (int*)  carve((size_t)(N+1)*4);
  int*   off1  = (int*)  carve((size_t)(N+1)*4);
  int*   tsum  = (int*)  carve((size_t)2*nt*4);
  int*   iperm = (int*)  carve((size_t)E*4);
  float* impO  = (float*)carve((size_t)E*4);
  int*   list1 = (int*)  carve((size_t)E*4);
  ERec*  rec   = (ERec*) carve((size_t)E*sizeof(ERec));
  u16*   heb   = (u16*)  carve((size_t)N*64*2);
  u16*   buf   = (u16*)  carve((size_t)E*64*2);      // xw / h' in-place
  float* gh    = (float*)carve((size_t)64*192*4);
  u16*   wfs[3];
  for(int l = 0; l < 3; l++) wfs[l] = (u16*)carve((size_t)4096*2);

  kzero<<<(4*N+255)/256, 256, 0, stream>>>(deg0, 4*N);
  kzero<<<(12288+255)/256, 256, 0, stream>>>((int*)gh, 12288);
  kdeg2<<<(E+255)/256, 256, 0, stream>>>(ei0, ei1, deg0, deg1, E);
  ktilesum<<<2*nt, 256, 0, stream>>>(deg0, deg1, tsum, N, nt);
  kmid<<<2, 256, 0, stream>>>(tsum, off0, off1, N, nt);
  kapply<<<2*nt, 256, 0, stream>>>(deg0, deg1, tsum, off0, off1, dinv, N, nt);
  kperm<<<(E+255)/256, 256, 0, stream>>>(ei0, ei1, nimp, dinv, batch, off0, cur0,
                                         rec, iperm, impO, E);
  kfillv<<<(E+255)/256, 256, 0, stream>>>(ei1, iperm, off1, cur1, list1, E);
  kprepw<<<5, 256, 0, stream>>>(Ws[0], wfs[0], Ws[1], wfs[1], Ws[2], wfs[2]);

  const int nbG = (E + 63)/64;
  const int nbA = (N + 3)/4;
  const int nbF = (E + 255)/256;   // contiguous 256-edge chunk per block

  kgemm0<<<nbG, 256, 0, stream>>>(edge_attr, buf, wfs[0], impO, iperm, E);
  kagg<<<nbA, 256, 0, stream>>>(buf, off0, off1, list1, heb, N);
  kfused<true ><<<nbF, 256, 0, stream>>>(buf, heb, (const f32x4*)rec, bs[0], wfs[1], gh + 0*64, E);
  kagg<<<nbA, 256, 0, stream>>>(buf, off0, off1, list1, heb, N);
  kfused<true ><<<nbF, 256, 0, stream>>>(buf, heb, (const f32x4*)rec, bs[1], wfs[2], gh + 1*64, E);
  kagg<<<nbA, 256, 0, stream>>>(buf, off0, off1, list1, heb, N);
  kfused<false><<<nbF, 256, 0, stream>>>(buf, heb, (const f32x4*)rec, bs[2], nullptr, gh + 2*64, E);
  kfinal<<<(12288+255)/256, 256, 0, stream>>>(gh, (float*)d_out, 12288);
}

// Round 5
// 428.730 us; speedup vs baseline: 1.1717x; 1.0087x over previous
//
#include <hip/hip_runtime.h>
#include <hip/hip_bf16.h>
#include <cstdint>
#include <cstddef>

typedef unsigned short u16;
typedef unsigned int   u32;
typedef short bf16x8 __attribute__((ext_vector_type(8)));   // 8 bf16 = 4 VGPRs
typedef float f32x4  __attribute__((ext_vector_type(4)));

// one 32-B record per sorted edge: a single cache line touch on scatter
struct __align__(16) ERec {
  u32 uv;            // u | (v<<16)
  float rc, iurc, ivrc;
  float ie; u32 bat; u32 pad0, pad1;
};
// one 16-B record per node: everything kperm needs for one endpoint
struct __align__(16) NRec { float dinv; float imp; int bat; int pad; };

#define NCOPY 8   // atomic privatization fan-out (blockIdx & 7)

__device__ __forceinline__ float bf2f(u16 v){ return __uint_as_float(((u32)v)<<16); }
__device__ __forceinline__ u16 f2bf(float f){
  u32 x = __float_as_uint(f);
  return (u16)((x + 0x7FFFu + ((x>>16)&1u)) >> 16);   // round-to-nearest-even
}
__device__ __forceinline__ void atomAddF(float* p, float v){ unsafeAtomicAdd(p, v); }
__device__ __forceinline__ float rlanef(float v, int q){
  return __int_as_float(__builtin_amdgcn_readlane(__float_as_int(v), q));
}

// ---------------- zero helper ----------------
__global__ void kzero(int* p, int n){
  int i = blockIdx.x*blockDim.x + threadIdx.x;
  if(i < n) p[i] = 0;
}

// ---------------- per-side degree counts, 8-way privatized ----------------
__global__ void kdeg2p(const int* __restrict__ ei0, const int* __restrict__ ei1,
                       int* __restrict__ deg0c, int* __restrict__ deg1c,
                       int N, int E){
  int e = blockIdx.x*blockDim.x + threadIdx.x;
  if(e >= E) return;
  const int c = blockIdx.x & (NCOPY-1);
  atomicAdd(&deg0c[c*N + ei0[e]], 1);
  atomicAdd(&deg1c[c*N + ei1[e]], 1);
}

// ---------------- fold copies -> totals + per-copy base offsets ----------------
__global__ void kreduce(const int* __restrict__ deg0c, const int* __restrict__ deg1c,
                        int* __restrict__ deg0, int* __restrict__ deg1,
                        int* __restrict__ cb0, int* __restrict__ cb1, int N){
  int i = blockIdx.x*blockDim.x + threadIdx.x;
  if(i < N){
    int s = 0;
    #pragma unroll
    for(int c = 0; c < NCOPY; c++){ int t = deg0c[c*N+i]; cb0[c*N+i] = s; s += t; }
    deg0[i] = s;
  } else if(i < 2*N){
    int j = i - N;
    int s = 0;
    #pragma unroll
    for(int c = 0; c < NCOPY; c++){ int t = deg1c[c*N+j]; cb1[c*N+j] = s; s += t; }
    deg1[j] = s;
  }
}

// ---------------- hierarchical exclusive scan (3 phases) ----------------
__global__ __launch_bounds__(256) void ktilesum(const int* __restrict__ deg0,
                                                const int* __restrict__ deg1,
                                                int* __restrict__ tsum,
                                                int N, int nt){
  __shared__ int sh[256];
  const int b = blockIdx.x;
  const int* deg = (b < nt) ? deg0 : deg1;
  const int tile = (b < nt) ? b : b - nt;
  const int t = threadIdx.x;
  const int i = tile*256 + t;
  sh[t] = (i < N) ? deg[i] : 0;
  __syncthreads();
  for(int s = 128; s > 0; s >>= 1){
    if(t < s) sh[t] += sh[t+s];
    __syncthreads();
  }
  if(t == 0) tsum[b] = sh[0];
}
__global__ __launch_bounds__(256) void kmid(int* __restrict__ tsum,
                                            int* __restrict__ off0,
                                            int* __restrict__ off1,
                                            int N, int nt){
  __shared__ int sh[256];
  const int b = blockIdx.x;
  int* ts = tsum + b*nt;
  const int t = threadIdx.x;
  sh[t] = (t < nt) ? ts[t] : 0;
  __syncthreads();
  for(int s = 1; s < 256; s <<= 1){
    int x = (t >= s) ? sh[t-s] : 0;
    __syncthreads();
    sh[t] += x;
    __syncthreads();
  }
  if(t < nt) ts[t] = (t == 0) ? 0 : sh[t-1];
  if(t == 255){ int* off = b ? off1 : off0; off[N] = sh[255]; }
}
// phase 3: intra-tile scan + tile base -> off[]; blocks b<nt also emit NRec
__global__ __launch_bounds__(256) void kapply(const int* __restrict__ deg0,
                                              const int* __restrict__ deg1,
                                              const int* __restrict__ tsum,
                                              int* __restrict__ off0,
                                              int* __restrict__ off1,
                                              const float* __restrict__ nimp,
                                              const int* __restrict__ batch,
                                              NRec* __restrict__ nrec,
                                              int N, int nt){
  __shared__ int sh[256];
  const int b = blockIdx.x;
  const int* deg = (b < nt) ? deg0 : deg1;
  int*       off = (b < nt) ? off0 : off1;
  const int tile = (b < nt) ? b : b - nt;
  const int base = tsum[b];
  const int t = threadIdx.x;
  const int i = tile*256 + t;
  sh[t] = (i < N) ? deg[i] : 0;
  __syncthreads();
  for(int s = 1; s < 256; s <<= 1){
    int x = (t >= s) ? sh[t-s] : 0;
    __syncthreads();
    sh[t] += x;
    __syncthreads();
  }
  if(i < N){
    off[i] = base + ((t == 0) ? 0 : sh[t-1]);
    if(b < nt){
      int d = deg0[i] + deg1[i];
      NRec r;
      r.dinv = (d > 1) ? (1.f/(float)d) : 0.f;   // deg==1 hyperedges dropped
      r.imp  = nimp[i];
      r.bat  = batch[i];
      r.pad  = 0;
      nrec[i] = r;
    }
  }
}

// ---------------- counting-sort (privatized) + v-list, merged ----------------
__global__ void kpermv(const int* __restrict__ ei0, const int* __restrict__ ei1,
                       const NRec* __restrict__ nrec,
                       const int* __restrict__ off0, const int* __restrict__ off1,
                       const int* __restrict__ cb0, const int* __restrict__ cb1,
                       int* __restrict__ cur0c, int* __restrict__ cur1c,
                       ERec* __restrict__ rec, int* __restrict__ iperm,
                       float* __restrict__ impO, int* __restrict__ list1,
                       int E, int N){
  int e = blockIdx.x*blockDim.x + threadIdx.x;
  if(e >= E) return;
  const int c = blockIdx.x & (NCOPY-1);
  int u = ei0[e], v = ei1[e];
  NRec ru = nrec[u];
  NRec rv = nrec[v];
  int pos = off0[u] + cb0[c*N+u] + atomicAdd(&cur0c[c*N+u], 1);
  float iu = ru.dinv, iv = rv.dinv;
  float rc = (iu > 0.f && iv > 0.f) ? (1.f/3.f)
           : ((iu > 0.f || iv > 0.f) ? 0.5f : 1.f);
  float ie = fminf(ru.imp, rv.imp);
  ERec r;
  r.uv = (u32)u | ((u32)v << 16);
  r.rc = rc; r.iurc = iu*rc; r.ivrc = iv*rc;
  r.ie = ie; r.bat = (u32)ru.bat; r.pad0 = 0; r.pad1 = 0;
  rec[pos]  = r;          // single-line scattered store (2x dwordx4)
  iperm[e]  = pos;        // coalesced
  impO[e]   = ie;         // coalesced
  int p1 = off1[v] + cb1[c*N+v] + atomicAdd(&cur1c[c*N+v], 1);
  list1[p1] = pos;        // scattered 4B
}

// ---------------- W -> fragment-ready layout (all 3 layers, one launch) -------
__global__ void kprepw(const float* __restrict__ W0, u16* __restrict__ wf0,
                       const float* __restrict__ W1, u16* __restrict__ wf1,
                       const float* __restrict__ W2, u16* __restrict__ wf2){
  const int b = blockIdx.x;
  const float* W; u16* wf; int NC, sbase;
  if(b == 0){ W = W0; wf = wf0; NC = 1; sbase = 0; }
  else if(b <= 2){ W = W1; wf = wf1; NC = 2; sbase = (b-1)*256; }
  else { W = W2; wf = wf2; NC = 2; sbase = (b-3)*256; }
  int s = sbase + threadIdx.x;
  if(s >= 4*NC*64) return;
  int lane = s & 63;
  int c    = (s >> 6) % NC;
  int tt   = s / (NC*64);
  int n  = tt*16 + (lane & 15);
  int k0 = c*32 + (lane >> 4)*8;
  #pragma unroll
  for(int j = 0; j < 8; j++)
    wf[(size_t)s*8 + j] = f2bf(W[(size_t)(k0 + j)*64 + n]);
}

// ---------------- layer 0 GEMM: sequential reads, scattered 128B-row writes ---
__global__ __launch_bounds__(256) void kgemm0(const float* __restrict__ srcf,
                                              u16* __restrict__ buf,
                                              const u16* __restrict__ wf,
                                              const float* __restrict__ impO,
                                              const int* __restrict__ iperm,
                                              int E){
  const int t    = threadIdx.x;
  const int wv   = t >> 6;
  const int lane = t & 63;
  const int quad = lane >> 4;
  const int l15  = lane & 15;
  const int row0 = blockIdx.x*64 + wv*16;
  if(row0 >= E) return;                      // E % 16 == 0

  bf16x8 bfr[4];
  #pragma unroll
  for(int i = 0; i < 4; i++)
    bfr[i] = *(const bf16x8*)(wf + ((size_t)i*64 + lane)*8);

  const int myrow = row0 + l15;              // ORIGINAL edge order: streaming
  const float* s = srcf + (size_t)myrow*32 + quad*8;
  const float sc = impO[myrow];              // coalesced
  const int ip = iperm[myrow];               // coalesced; dest row in sorted space
  f32x4 v0 = *(const f32x4*)s;
  f32x4 v1 = *(const f32x4*)(s+4);
  bf16x8 afr;
  afr[0]=(short)f2bf(v0.x*sc); afr[1]=(short)f2bf(v0.y*sc);
  afr[2]=(short)f2bf(v0.z*sc); afr[3]=(short)f2bf(v0.w*sc);
  afr[4]=(short)f2bf(v1.x*sc); afr[5]=(short)f2bf(v1.y*sc);
  afr[6]=(short)f2bf(v1.z*sc); afr[7]=(short)f2bf(v1.w*sc);

  // dest rows for the 4 tile-rows this quad stores (one bpermute per r)
  int dr[4];
  #pragma unroll
  for(int r = 0; r < 4; r++) dr[r] = __shfl(ip, quad*4 + r);

  #pragma unroll
  for(int tt = 0; tt < 4; tt++){
    f32x4 a = {0.f,0.f,0.f,0.f};
    a = __builtin_amdgcn_mfma_f32_16x16x32_bf16(afr, bfr[tt], a, 0, 0, 0);
    const int n = tt*16 + l15;
    #pragma unroll
    for(int r = 0; r < 4; r++)
      buf[(size_t)dr[r]*64 + n] = f2bf(a[r]);
  }
}

// ---------------- aggregate: 8 rows per wave-instr, col-block layout ----------
// lane = (rsub = lane>>3 row-in-group, cb = lane&7 col-block of 8 cols)
__global__ __launch_bounds__(256) void kagg(const u16* __restrict__ buf,
                                            const int* __restrict__ off0,
                                            const int* __restrict__ off1,
                                            const int* __restrict__ list1,
                                            u16* __restrict__ heb, int N){
  const int t = threadIdx.x, wv = t >> 6, lane = t & 63;
  const int n = blockIdx.x*4 + wv;
  if(n >= N) return;
  const int rsub = lane >> 3, cb = lane & 7;
  float acc[8];
  #pragma unroll
  for(int k = 0; k < 8; k++) acc[k] = 0.f;

  auto accum = [&](uint4 x){
    acc[0] += bf2f((u16)x.x); acc[1] += bf2f((u16)(x.x>>16));
    acc[2] += bf2f((u16)x.y); acc[3] += bf2f((u16)(x.y>>16));
    acc[4] += bf2f((u16)x.z); acc[5] += bf2f((u16)(x.z>>16));
    acc[6] += bf2f((u16)x.w); acc[7] += bf2f((u16)(x.w>>16));
  };
  const uint4 zero4 = {0,0,0,0};

  // u-side: contiguous rows [off0[n], off0[n+1])
  {
    const int s0 = off0[n], d0 = off0[n+1] - s0;
    const u16* base = buf + (size_t)s0*64;
    int j = 0;
    for(; j + 8 <= d0; j += 8)
      accum(*(const uint4*)(base + (size_t)(j+rsub)*64 + cb*8));
    if(j < d0)
      accum((rsub < d0-j) ? *(const uint4*)(base + (size_t)(j+rsub)*64 + cb*8) : zero4);
  }
  // v-side: random rows via list1
  {
    const int s1 = off1[n], d1 = off1[n+1] - s1;
    int j = 0;
    for(; j + 8 <= d1; j += 8){
      int e = list1[s1 + j + rsub];
      accum(*(const uint4*)(buf + (size_t)e*64 + cb*8));
    }
    if(j < d1){
      uint4 x = zero4;
      if(rsub < d1-j){
        int e = list1[s1 + j + rsub];
        x = *(const uint4*)(buf + (size_t)e*64 + cb*8);
      }
      accum(x);
    }
  }
  // reduce across rsub (lanes differing in bits 3..5)
  #pragma unroll
  for(int m = 8; m <= 32; m <<= 1)
    #pragma unroll
    for(int k = 0; k < 8; k++) acc[k] += __shfl_xor(acc[k], m);
  // write: rsub==0 lanes store 8 cols (16 B)
  if(rsub == 0){
    u32 o[4];
    #pragma unroll
    for(int k = 0; k < 4; k++)
      o[k] = (u32)f2bf(acc[2*k]) | ((u32)f2bf(acc[2*k+1]) << 16);
    *(uint4*)(heb + (size_t)n*64 + cb*8) = make_uint4(o[0],o[1],o[2],o[3]);
  }
}

// ---------------- fused: gather + epilogue + register-pool (+ GEMM) ------------
// issue-48 -> prefetch-desc -> consume; readlane broadcasts; ERec descriptors.
template<bool DO_GEMM>
__global__ __launch_bounds__(256, 3) void kfused(u16* __restrict__ buf,   // r/w
                                                 const u16* __restrict__ heb,
                                                 const f32x4* __restrict__ rec4, // ERec as 2x f32x4
                                                 const float* __restrict__ bias,
                                                 const u16* __restrict__ wf,
                                                 float* __restrict__ ghL,  // gh + layer*64
                                                 int E){
  constexpr int HTSZ = DO_GEMM ? 4*16*72 : 4;       // 16 rows x 72 per wave
  __shared__ __align__(16) u16 hT[HTSZ];
  const int t = threadIdx.x, wv = t >> 6, lane = t & 63;
  const int quad = lane >> 4, l15 = lane & 15;
  const float bd = bias[lane];

  bf16x8 bfr[8];
  if(DO_GEMM){
    #pragma unroll
    for(int i = 0; i < 8; i++)
      bfr[i] = *(const bf16x8*)(wf + ((size_t)i*64 + lane)*8);
  }

  float pool = 0.f;
  int cur_g = -1;
  // wave-uniform base row, forced into SGPR
  const int base = __builtin_amdgcn_readfirstlane((int)(blockIdx.x*256) + wv*64);
  u16* hTw = DO_GEMM ? &hT[wv*1152] : &hT[0];

  // descriptor bank for group 0 (lane l15 holds edge base+l15)
  u32 uvp = 0; f32x4 cf = {0.f,0.f,0.f,0.f}; int bt = 0;
  if(base < E){                              // E % 16 == 0 -> base+15 < E
    f32x4 w0 = rec4[(size_t)(base+l15)*2];
    f32x4 w1 = rec4[(size_t)(base+l15)*2 + 1];
    uvp = __float_as_uint(w0.x);
    cf.x = w0.y; cf.y = w0.z; cf.z = w0.w; cf.w = w1.x;
    bt  = __float_as_int(w1.y);
  }

  #pragma unroll
  for(int it = 0; it < 4; it++){
    const int r0 = base + it*16;
    if(r0 < E){
      // ---- issue all 48 gathers (scalar bases, imm offsets for bv) ----
      u16 bv[16], hu[16], hv[16];
      const u16* bufr = buf + (size_t)r0*64;          // SGPR base
      #pragma unroll
      for(int q = 0; q < 16; q++){
        const u32 uv = (u32)__builtin_amdgcn_readlane((int)uvp, q);  // SGPR
        hv[q] = heb[(size_t)(uv >> 16)*64 + lane];
        hu[q] = heb[(size_t)(uv & 0xffffu)*64 + lane];
        bv[q] = bufr[q*64 + lane];
      }
      // ---- prefetch next group's descriptors ----
      u32 uvpN = uvp; f32x4 cfN = cf; int btN = bt;
      if(it < 3){
        const int r1 = r0 + 16;
        if(r1 < E){
          f32x4 w0 = rec4[(size_t)(r1+l15)*2];
          f32x4 w1 = rec4[(size_t)(r1+l15)*2 + 1];
          uvpN = __float_as_uint(w0.x);
          cfN.x = w0.y; cfN.y = w0.z; cfN.z = w0.w; cfN.w = w1.x;
          btN  = __float_as_int(w1.y);
        }
      }
      // ---- batch bookkeeping: uniform fast path (boundaries are rare) ----
      const int bFirst = __builtin_amdgcn_readlane(bt, 0);
      const int bLast  = __builtin_amdgcn_readlane(bt, 15);
      if(bFirst != cur_g){
        if(cur_g >= 0) atomAddF(&ghL[cur_g*192 + lane], pool);
        pool = 0.f; cur_g = bFirst;
      }
      if(bFirst == bLast){
        #pragma unroll
        for(int q = 0; q < 16; q++){
          const float rc   = rlanef(cf.x, q);
          const float iurc = rlanef(cf.y, q);
          const float ivrc = rlanef(cf.z, q);
          const float ie   = rlanef(cf.w, q);
          float o = fmaxf(fmaf(bf2f(bv[q]), rc,
                          fmaf(bf2f(hu[q]), iurc,
                          fmaf(bf2f(hv[q]), ivrc, bd))), 0.f) * ie;
          pool += o;
          if(DO_GEMM) hTw[q*72 + lane] = f2bf(o);
        }
      } else {
        #pragma unroll
        for(int q = 0; q < 16; q++){
          const float rc   = rlanef(cf.x, q);
          const float iurc = rlanef(cf.y, q);
          const float ivrc = rlanef(cf.z, q);
          const float ie   = rlanef(cf.w, q);
          const int   bq   = __builtin_amdgcn_readlane(bt, q);
          float o = fmaxf(fmaf(bf2f(bv[q]), rc,
                          fmaf(bf2f(hu[q]), iurc,
                          fmaf(bf2f(hv[q]), ivrc, bd))), 0.f) * ie;
          if(bq != cur_g){                        // wave-uniform branch
            if(cur_g >= 0) atomAddF(&ghL[cur_g*192 + lane], pool);
            pool = 0.f; cur_g = bq;
          }
          pool += o;
          if(DO_GEMM) hTw[q*72 + lane] = f2bf(o);
        }
      }
      // ---- stage 2: MFMA these 16 rows (wave-local LDS, no barrier) ----
      if(DO_GEMM){
        bf16x8 afr0 = *(const bf16x8*)&hTw[l15*72 + quad*8];
        bf16x8 afr1 = *(const bf16x8*)&hTw[l15*72 + 32 + quad*8];
        #pragma unroll
        for(int tt = 0; tt < 4; tt++){
          f32x4 a = {0.f,0.f,0.f,0.f};
          a = __builtin_amdgcn_mfma_f32_16x16x32_bf16(afr0, bfr[tt*2+0], a, 0, 0, 0);
          a = __builtin_amdgcn_mfma_f32_16x16x32_bf16(afr1, bfr[tt*2+1], a, 0, 0, 0);
          const int n = tt*16 + l15;
          #pragma unroll
          for(int r = 0; r < 4; r++)
            buf[(size_t)(r0 + quad*4 + r)*64 + n] = f2bf(a[r]);
        }
      }
      uvp = uvpN; cf = cfN; bt = btN;
    }
  }
  if(cur_g >= 0) atomAddF(&ghL[cur_g*192 + lane], pool);
}

__global__ void kfinal(const float* __restrict__ gh, float* __restrict__ out, int n){
  int i = blockIdx.x*blockDim.x + threadIdx.x;
  if(i < n) out[i] = gh[i];   // reference output dtype = float32
}

// ---------------- host ----------------
extern "C" void kernel_launch(void* const* d_in, const int* in_sizes, int n_in,
                              void* d_out, int out_size, void* d_ws, size_t ws_size,
                              hipStream_t stream) {
  const float* edge_attr = (const float*)d_in[1];
  const int*   ei        = (const int*)d_in[2];
  const int*   batch     = (const int*)d_in[3];
  const float* nimp      = (const float*)d_in[4];
  const float* Ws[3] = { (const float*)d_in[5], (const float*)d_in[7], (const float*)d_in[9] };
  const float* bs[3] = { (const float*)d_in[6], (const float*)d_in[8], (const float*)d_in[10] };

  const int E = in_sizes[1] / 32;   // edge_attr is (E, 32)
  const int N = in_sizes[4];        // node_imp is (N,)
  const int* ei0 = ei;
  const int* ei1 = ei + E;

  char* p = (char*)d_ws;
  auto carve = [&](size_t bytes)->char*{
    char* r = p; p += (bytes + 255) & ~(size_t)255; return r;
  };
  const int nt = (N + 255)/256;
  // privatized counters/bases: deg0c|deg1c|cur0c|cur1c, each NCOPY*N
  int*   deg0c = (int*)  carve((size_t)4*NCOPY*N*4);
  int*   deg1c = deg0c + NCOPY*N;
  int*   cur0c = deg0c + 2*NCOPY*N;
  int*   cur1c = deg0c + 3*NCOPY*N;
  int*   cb0   = (int*)  carve((size_t)2*NCOPY*N*4);
  int*   cb1   = cb0 + NCOPY*N;
  int*   deg0  = (int*)  carve((size_t)2*N*4);
  int*   deg1  = deg0 + N;
  NRec*  nrec  = (NRec*) carve((size_t)N*sizeof(NRec));
  int*   off0  = (int*)  carve((size_t)(N+1)*4);
  int*   off1  = (int*)  carve((size_t)(N+1)*4);
  int*   tsum  = (int*)  carve((size_t)2*nt*4);
  int*   iperm = (int*)  carve((size_t)E*4);
  float* impO  = (float*)carve((size_t)E*4);
  int*   list1 = (int*)  carve((size_t)E*4);
  ERec*  rec   = (ERec*) carve((size_t)E*sizeof(ERec));
  u16*   heb   = (u16*)  carve((size_t)N*64*2);
  u16*   buf   = (u16*)  carve((size_t)E*64*2);      // xw / h' in-place
  float* gh    = (float*)carve((size_t)64*192*4);
  u16*   wfs[3];
  for(int l = 0; l < 3; l++) wfs[l] = (u16*)carve((size_t)4096*2);

  kzero<<<(4*NCOPY*N+255)/256, 256, 0, stream>>>(deg0c, 4*NCOPY*N);
  kzero<<<(12288+255)/256, 256, 0, stream>>>((int*)gh, 12288);
  kdeg2p<<<(E+255)/256, 256, 0, stream>>>(ei0, ei1, deg0c, deg1c, N, E);
  kreduce<<<(2*N+255)/256, 256, 0, stream>>>(deg0c, deg1c, deg0, deg1, cb0, cb1, N);
  ktilesum<<<2*nt, 256, 0, stream>>>(deg0, deg1, tsum, N, nt);
  kmid<<<2, 256, 0, stream>>>(tsum, off0, off1, N, nt);
  kapply<<<2*nt, 256, 0, stream>>>(deg0, deg1, tsum, off0, off1, nimp, batch, nrec, N, nt);
  kpermv<<<(E+255)/256, 256, 0, stream>>>(ei0, ei1, nrec, off0, off1, cb0, cb1,
                                          cur0c, cur1c, rec, iperm, impO, list1, E, N);
  kprepw<<<5, 256, 0, stream>>>(Ws[0], wfs[0], Ws[1], wfs[1], Ws[2], wfs[2]);

  const int nbG = (E + 63)/64;
  const int nbA = (N + 3)/4;
  const int nbF = (E + 255)/256;   // contiguous 256-edge chunk per block

  kgemm0<<<nbG, 256, 0, stream>>>(edge_attr, buf, wfs[0], impO, iperm, E);
  kagg<<<nbA, 256, 0, stream>>>(buf, off0, off1, list1, heb, N);
  kfused<true ><<<nbF, 256, 0, stream>>>(buf, heb, (const f32x4*)rec, bs[0], wfs[1], gh + 0*64, E);
  kagg<<<nbA, 256, 0, stream>>>(buf, off0, off1, list1, heb, N);
  kfused<true ><<<nbF, 256, 0, stream>>>(buf, heb, (const f32x4*)rec, bs[1], wfs[2], gh + 1*64, E);
  kagg<<<nbA, 256, 0, stream>>>(buf, off0, off1, list1, heb, N);
  kfused<false><<<nbF, 256, 0, stream>>>(buf, heb, (const f32x4*)rec, bs[2], nullptr, gh + 2*64, E);
  kfinal<<<(12288+255)/256, 256, 0, stream>>>(gh, (float*)d_out, 12288);
}